// Round 12
// baseline (128.867 us; speedup 1.0000x reference)
//
#include <hip/hip_runtime.h>
#include <math.h>

#define BS 8
#define NQ 8192
#define NT 512
#define NTHR 512
#define CHUNKS 16            // NQ / NTHR columns per thread (SAP scan)
#define NW (NTHR / 64)       // 8 waves
#define MAXL (NT + 2)
#define QCAP 4608            // auction queue capacity (shorts)
#define AUC_RCAP 400         // round cap: 400*8 kicks + 512 <= QCAP
#define KMASK 0xFFFFFFFFFFFFE000ull
#define CFB 240              // persistent C-fill blocks

#define DINF (__builtin_inf())

typedef float vf4 __attribute__((ext_vector_type(4)));

// f32 cost, FMA-contraction-free, bit-identical everywhere it is computed.
__device__ __forceinline__ float cost_f32(float qx, float qy, float cl, float tx, float ty) {
    float dx = __fsub_rn(qx, tx);
    float dy = __fsub_rn(qy, ty);
    float d2 = __fadd_rn(__fmul_rn(dx, dx), __fmul_rn(dy, dy));
    float d  = __fsqrt_rn(d2);
    return __fadd_rn(__fmul_rn(0.5f, d), cl);
}

__device__ __forceinline__ float cls_f32(float x) {
    float s;
    if (x >= 0.0f) { float e = expf(-x); s = 1.0f / (1.0f + e); }
    else           { float e = expf(x);  s = e / (1.0f + e); }
    return __fsub_rn(1.0f, s);
}

// packed (value,idx) key: non-negative doubles compare as u64 bits;
// low 13 bits hold column idx -> min == (min value, lowest idx).
__device__ __forceinline__ unsigned long long pack_key(double v, int idx) {
    double c = fmax(v, 0.0);
    return (((unsigned long long)__double_as_longlong(c)) & KMASK)
         | (unsigned long long)((unsigned)idx & 0x1FFFu);
}
__device__ __forceinline__ double key_val(unsigned long long k) {
    return __longlong_as_double((long long)(k & KMASK));
}

// 512 threads = 8 row-waves per block; batch data (pred + computed cls)
// staged once in 96KB LDS, 8x reuse. Designated blocks also write cls to
// global (consumed by fused). Per lane: even/odd top-2 chains (2x ILP),
// merged with lowest-index tie-break. bnd = certified lower bound on every
// column NOT in the candidate list. Also global (min,argmin) -> u0/jm.
__global__ __launch_bounds__(512) void cand_kernel(
    const float* __restrict__ logits,
    const float* __restrict__ pred_points,
    const float* __restrict__ tgt_points,
    float* __restrict__ cls_out,
    float* __restrict__ u0, int* __restrict__ jm, float* __restrict__ bnd,
    float* __restrict__ ccost, unsigned short* __restrict__ cidx) {
    extern __shared__ char sm[];
    float2* pd = (float2*)sm;            // 8192 float2 = 64KB
    float*  cl = (float*)(pd + NQ);      // 8192 float  = 32KB

    const int tid = threadIdx.x;
    const int b   = blockIdx.x >> 6;     // 64 blocks per batch

    // stage pred as float4 (two points per load)
    const float4* p4 = (const float4*)(pred_points + (size_t)b * NQ * 2);
    for (int t = tid; t < NQ / 2; t += 512) ((float4*)pd)[t] = p4[t];
    // stage cls (computed from logits); one block per batch writes it out
    const bool wr = ((blockIdx.x & 63) == 0);
    for (int t = tid; t < NQ; t += 512) {
        const float c = cls_f32(logits[b * NQ + t]);
        cl[t] = c;
        if (wr) cls_out[b * NQ + t] = c;
    }
    __syncthreads();

    const int w = tid >> 6, lane = tid & 63;
    const int g = blockIdx.x * 8 + w;    // 0..4095
    const int i = g & (NT - 1);
    const float tx = tgt_points[(b * NT + i) * 2 + 0];
    const float ty = tgt_points[(b * NT + i) * 2 + 1];

    float a0 = DINF, a1 = DINF, am = DINF; int ai0 = 0, ai1 = 0;
    float b0 = DINF, b1 = DINF, bm = DINF; int bi0 = 0, bi1 = 0;
    for (int k = 0; k < NQ / 128; ++k) {     // 64 iters, 2 cols each
        const int c = k * 128 + 2 * lane;
        const float4 qq  = ((const float4*)pd)[c >> 1];
        const float2 cc2 = ((const float2*)cl)[c >> 1];
        const float cva = cost_f32(qq.x, qq.y, cc2.x, tx, ty);
        const float cvb = cost_f32(qq.z, qq.w, cc2.y, tx, ty);
        if (cva < a1) { am = a1; if (cva < a0) { a1 = a0; ai1 = ai0; a0 = cva; ai0 = c; } else { a1 = cva; ai1 = c; } }
        else am = fminf(am, cva);
        if (cvb < b1) { bm = b1; if (cvb < b0) { b1 = b0; bi1 = bi0; b0 = cvb; bi0 = c + 1; } else { b1 = cvb; bi1 = c + 1; } }
        else bm = fminf(bm, cvb);
    }
    // merge two sorted pairs, exact lowest-index tie-break
    float t0v, t1v, s3v; int t0i, t1i;
    const bool bWins = (b0 < a0) || (b0 == a0 && bi0 < ai0);
    if (!bWins) {
        t0v = a0; t0i = ai0;
        const bool a1Wins = (a1 < b0) || (a1 == b0 && ai1 < bi0);
        if (a1Wins) { t1v = a1; t1i = ai1; s3v = b0; }
        else        { t1v = b0; t1i = bi0; s3v = fminf(a1, b1); }
    } else {
        t0v = b0; t0i = bi0;
        const bool b1Wins = (b1 < a0) || (b1 == a0 && bi1 < ai0);
        if (b1Wins) { t1v = b1; t1i = bi1; s3v = a0; }
        else        { t1v = a0; t1i = ai0; s3v = fminf(b1, a1); }
    }
    const float bb0 = fminf(fminf(am, bm), s3v);

    ((float2*)(ccost + ((size_t)g << 7)))[lane] = make_float2(t0v, t1v);
    ((ushort2*)(cidx + ((size_t)g << 7)))[lane] =
        make_ushort2((unsigned short)t0i, (unsigned short)t1i);
    float bv = t0v; int bc = t0i; float bb = bb0;
    for (int off = 32; off > 0; off >>= 1) {
        float ov = __shfl_down(bv, off, 64);
        int   oc = __shfl_down(bc, off, 64);
        float ob = __shfl_down(bb, off, 64);
        if (ov < bv || (ov == bv && oc < bc)) { bv = ov; bc = oc; }
        bb = fminf(bb, ob);
    }
    if (lane == 0) { u0[g] = bv; jm[g] = bc; bnd[g] = bb; }
}

// Fused: blocks [0,BS) = exact LSA (greedy -> persistent-slot auction ->
// full-scan SAP); blocks [BS, BS+CFB) = persistent grid-stride C fill.
__global__ __launch_bounds__(NTHR, 1) void fused_kernel(
    const float* __restrict__ pred_points,
    const float* __restrict__ tgt_points,
    const float* __restrict__ cls,
    const float* __restrict__ u0,
    const int* __restrict__ jm,
    const float* __restrict__ bnd,
    const float* __restrict__ ccost,
    const unsigned short* __restrict__ cidx,
    float* __restrict__ C,
    float* __restrict__ out_rows,
    float* __restrict__ out_cols) {
    const int tid = threadIdx.x;

    // ---------------- persistent C-fill branch ----------------
    if (blockIdx.x >= BS) {
        const int cfid = blockIdx.x - BS;            // 0..CFB-1
        const int ngrp = BS * NQ / 16;               // 4096 groups of 16 queries
        const int g32  = tid & 31;
        for (int grp = cfid; grp < ngrp; grp += CFB) {
            const int bq = (grp << 4) + (tid >> 5);  // 16 queries per group
            const int b  = bq >> 13;
            const float2 q = ((const float2*)pred_points)[bq];
            const float cl = cls[bq];
            const float* tb = tgt_points + b * NT * 2;
#pragma unroll
            for (int s = 0; s < 4; ++s) {
                const int t = g32 * 4 + s * 128;
                float4 A  = *(const float4*)(tb + t * 2);
                float4 Bv = *(const float4*)(tb + t * 2 + 4);
                vf4 r;
                r.x = cost_f32(q.x, q.y, cl, A.x,  A.y);
                r.y = cost_f32(q.x, q.y, cl, A.z,  A.w);
                r.z = cost_f32(q.x, q.y, cl, Bv.x, Bv.y);
                r.w = cost_f32(q.x, q.y, cl, Bv.z, Bv.w);
                __builtin_nontemporal_store(r, (vf4*)(C + (size_t)bq * NT + t));
            }
        }
        return;
    }

    // ---------------- LSA branch ----------------
    const int b = blockIdx.x;
    extern __shared__ char smem[];
    double* v_s       = (double*)smem;                       // 8192
    double* u_s       = v_s + NQ;                            // 512
    double* l_minv    = u_s + NT;                            // MAXL
    double* l_v       = l_minv + MAXL;                       // MAXL
    double* bid_m2    = l_v + MAXL;                          // 8
    unsigned long long* p_k = (unsigned long long*)(bid_m2 + 8);  // NW
    float*  tg        = (float*)(p_k + NW);                  // 1024
    float*  bnd_s     = tg + NT * 2;                         // 512
    float*  bid_c     = bnd_s + NT;                          // 8
    int*    s_int     = (int*)(bid_c + 8);                   // 4
    int*    bid_j     = s_int + 4;                           // 8
    short*  bid_row   = (short*)(bid_j + 8);                 // 8
    short*  wrow      = bid_row + 8;                         // 8
    short*  path_s    = wrow + 8;                            // 8192
    short*  row4col_s = path_s + NQ;                         // 8192
    short*  col4row_s = row4col_s + NQ;                      // 512
    short*  jm_s      = col4row_s + NT;                      // 512
    short*  dflag     = jm_s + NT;                           // 512
    short*  sap_s     = dflag + NT;                          // 512
    short*  l_k       = sap_s + NT;                          // MAXL
    short*  l_r       = l_k + MAXL;                          // MAXL
    short*  queue_s   = l_r + MAXL;                          // QCAP

    for (int c = tid; c < NQ; c += NTHR) { row4col_s[c] = -1; v_s[c] = 0.0; }
    for (int r = tid; r < NT; r += NTHR) {
        col4row_s[r] = -1;
        u_s[r]   = (double)u0[b * NT + r];
        jm_s[r]  = (short)jm[b * NT + r];
        bnd_s[r] = bnd[b * NT + r];
    }
    for (int t = tid; t < NT * 2; t += NTHR) tg[t] = tgt_points[b * NT * 2 + t];

    // per-thread column state for SAP (registers)
    float  qx[CHUNKS], qy[CHUNKS], cl[CHUNKS];
    double sh[CHUNKS];
#pragma unroll
    for (int j = 0; j < CHUNKS; ++j) {
        int c = j * NTHR + tid;
        qx[j] = pred_points[(b * NQ + c) * 2 + 0];
        qy[j] = pred_points[(b * NQ + c) * 2 + 1];
        cl[j] = cls[b * NQ + c];
    }
    __syncthreads();

    // ---- parallel greedy: row r gets jm[r] iff no earlier row claims it
    {
        const int r = tid;
        const short jmr = jm_s[r];
        int conflict = 0;
        for (int r2 = 0; r2 < r; ++r2) conflict |= (jm_s[r2] == jmr) ? 1 : 0;
        dflag[r] = (short)conflict;
        if (!conflict) { col4row_s[r] = jmr; row4col_s[jmr] = (short)r; }
        __syncthreads();
        int rank = 0;
        for (int r2 = 0; r2 < r; ++r2) rank += dflag[r2];
        if (conflict) queue_s[rank] = (short)r;
        if (r == NT - 1) s_int[0] = rank + conflict;   // tail0
        __syncthreads();
    }

    // ---- persistent-slot auction: each wave retains a row until it wins a
    // column (or cert-fails); dup-losers re-bid IMMEDIATELY next round with
    // candidates kept in registers. Exactness: each column commits <=1
    // winner/round; v only decreases (min guard); u[i]=m2, v[j1]=c-m2 keeps
    // duals feasible + CS (stale m2 <= true m2, and v_old >= c-m2_stale since
    // j1 untouched this round). Cert-fail / round-cap -> exact SAP finisher.
    {
        if (tid == 0) {
            int head = 0, tail = s_int[0];
            int any = 0;
            for (int w2 = 0; w2 < NW; ++w2) {
                wrow[w2] = (head < tail) ? queue_s[head++] : -1;
                any |= (wrow[w2] >= 0) ? 1 : 0;
            }
            s_int[0] = head; s_int[1] = tail; s_int[2] = 0; s_int[3] = any;
        }
        __syncthreads();

        const int w = tid >> 6, lane = tid & 63;
        int creg_row = -1;
        float2 cc; ushort2 ci;
        int rounds = 0;
        while (s_int[3]) {
            const int row = wrow[w];
            if (row >= 0) {
                if (row != creg_row) {   // fresh row: load candidates
                    const int g = (b << 9) + row;
                    cc = ((const float2*)(ccost + ((size_t)g << 7)))[lane];
                    ci = ((const ushort2*)(cidx + ((size_t)g << 7)))[lane];
                    creg_row = row;
                }
                const double rr0 = (double)cc.x - v_s[ci.x];
                const double rr1 = (double)cc.y - v_s[ci.y];
                const unsigned long long q0 = pack_key(rr0, ci.x);
                const unsigned long long q1 = pack_key(rr1, ci.y);
                unsigned long long k1  = q0 < q1 ? q0 : q1;
                unsigned long long m2b = (q0 < q1 ? q1 : q0) & KMASK;
                for (int m = 32; m > 0; m >>= 1) {
                    unsigned long long ok1 = __shfl_xor(k1, m, 64);
                    unsigned long long om2 = __shfl_xor(m2b, m, 64);
                    unsigned long long lo  = (ok1 < k1) ? ok1 : k1;
                    unsigned long long hiv = ((ok1 < k1) ? k1 : ok1) & KMASK;
                    k1 = lo;
                    if (om2 < m2b) m2b = om2;
                    if (hiv < m2b) m2b = hiv;
                }
                const double m2d = key_val(m2b);
                if (q0 == k1) bid_c[w] = cc.x;     // unique winner entry
                if (q1 == k1) bid_c[w] = cc.y;
                if (lane == 0) {
                    bid_m2[w] = m2d;
                    bid_j[w]  = (m2d < (double)bnd_s[row]) ? (int)(k1 & 0x1FFFull) : -1;
                }
            }
            __syncthreads();                               // B1
            if (tid == 0) {
                int head = s_int[0], tail = s_int[1], ns = s_int[2];
                int cj[NW]; int nc = 0;
                for (int w2 = 0; w2 < NW; ++w2) {
                    const int r2 = wrow[w2];
                    if (r2 < 0) continue;
                    const int j1 = bid_j[w2];
                    if (j1 < 0) { sap_s[ns++] = (short)r2; wrow[w2] = -1; continue; }
                    int dup = 0;
                    for (int x = 0; x < nc; ++x) dup |= (cj[x] == j1);
                    if (dup) continue;                     // retain: retry next round
                    cj[nc++] = j1;
                    const double m2d = bid_m2[w2];
                    const int ko = row4col_s[j1];
                    row4col_s[j1] = (short)r2;
                    col4row_s[r2] = (short)j1;
                    u_s[r2] = m2d;
                    const double nv = (double)bid_c[w2] - m2d;
                    if (nv < v_s[j1]) v_s[j1] = nv;
                    if (ko >= 0) { col4row_s[ko] = -1; queue_s[tail++] = (short)ko; }
                    wrow[w2] = -1;
                }
                for (int w2 = 0; w2 < NW; ++w2)            // refill free slots
                    if (wrow[w2] < 0 && head < tail) wrow[w2] = queue_s[head++];
                int any = 0;
                for (int w2 = 0; w2 < NW; ++w2) any |= (wrow[w2] >= 0) ? 1 : 0;
                if (any && rounds >= AUC_RCAP) {           // cap -> dump to SAP
                    for (int w2 = 0; w2 < NW; ++w2)
                        if (wrow[w2] >= 0) { sap_s[ns++] = wrow[w2]; wrow[w2] = -1; }
                    while (head < tail) sap_s[ns++] = queue_s[head++];
                    any = 0;
                }
                s_int[0] = head; s_int[1] = tail; s_int[2] = ns; s_int[3] = any;
            }
            __syncthreads();                               // B2
            ++rounds;
        }
    }

    // ---- SAP for leftovers (exact full scan, v in LDS)
    const int NL = s_int[2];
    for (int di = 0; di < NL; ++di) {
        const int cur_row = sap_s[di];
#pragma unroll
        for (int j = 0; j < CHUNKS; ++j) sh[j] = DINF;
        int    i    = cur_row;
        double minv = 0.0;
        int    len  = 0;
        int    sink = -1;

        for (;;) {
            const double w  = minv - u_s[i];
            const float  tx = tg[i * 2 + 0];
            const float  ty = tg[i * 2 + 1];

            double best = DINF;
            int bestc = NQ;
#pragma unroll
            for (int j = 0; j < CHUNKS; ++j) {
                const int c = j * NTHR + tid;
                float  cf = cost_f32(qx[j], qy[j], cl[j], tx, ty);
                double rr = (w + (double)cf) - v_s[c];
                if (rr < sh[j]) { sh[j] = rr; path_s[c] = (short)i; }
                if (sh[j] < best) { best = sh[j]; bestc = c; }
            }
            unsigned long long bkey = pack_key(best, bestc);
            for (int off = 32; off > 0; off >>= 1) {
                unsigned long long ok = __shfl_down(bkey, off, 64);
                if (ok < bkey) bkey = ok;
            }
            const int par = len & 1;
            if ((tid & 63) == 0) p_k[tid >> 6] = bkey;
            (void)par;
            __syncthreads();                               // B1
            bkey = p_k[tid & (NW - 1)];
            for (int m = NW >> 1; m > 0; m >>= 1) {
                unsigned long long ok = __shfl_xor(bkey, m, 64);
                if (ok < bkey) bkey = ok;
            }
            minv = key_val(bkey);
            const int k  = (int)(bkey & 0x1FFFull);
            const int rk = row4col_s[k];     // stable during Dijkstra
            if (tid == 0) {
                l_v[len] = v_s[k]; v_s[k] = -DINF;   // neutralize column
                l_k[len] = (short)k; l_minv[len] = minv; l_r[len] = (short)rk;
            }
            if ((k & (NTHR - 1)) == tid) {   // owner freezes its sh register
                const int jj = k >> 9;
#pragma unroll
                for (int j = 0; j < CHUNKS; ++j)
                    if (j == jj) sh[j] = DINF;
            }
            __syncthreads();                               // B2
            ++len;
            if (rk < 0) { sink = k; break; }
            i = rk;
        }

        const int L = len;
        for (int e = tid; e < L; e += NTHR) {
            const int rk2 = l_r[e];
            if (rk2 >= 0) u_s[rk2] += minv - l_minv[e];
        }
        if (tid == 0) u_s[cur_row] += minv;
        for (int e = tid; e < L; e += NTHR)    // restore + v duals (distinct k)
            v_s[l_k[e]] = l_v[e] - (minv - l_minv[e]);
        __syncthreads();
        if (tid == 0) {   // augment along the alternating path
            int j = sink;
            for (;;) {
                const int ii = path_s[j];
                row4col_s[j] = (short)ii;
                const int t = col4row_s[ii];
                col4row_s[ii] = (short)j;
                j = t;
                if (ii == cur_row) break;
            }
        }
        __syncthreads();
    }

    // row_ind = sorted(col4row), col_ind = argsort(col4row); values distinct
    for (int r = tid; r < NT; r += NTHR) {
        const int q = col4row_s[r];
        int rank = 0;
        for (int r2 = 0; r2 < NT; ++r2) rank += (col4row_s[r2] < q) ? 1 : 0;
        out_rows[b * NT + rank] = (float)q;
        out_cols[b * NT + rank] = (float)r;
    }
}

extern "C" void kernel_launch(void* const* d_in, const int* in_sizes, int n_in,
                              void* d_out, int out_size, void* d_ws, size_t ws_size,
                              hipStream_t stream) {
    const float* logits = (const float*)d_in[0];  // (8, 8192, 1)
    const float* pred   = (const float*)d_in[1];  // (8, 8192, 2)
    const float* tgt    = (const float*)d_in[2];  // (8, 512, 2)

    float* out  = (float*)d_out;
    float* C    = out;                                   // BS*NQ*NT
    float* orow = out + (size_t)BS * NQ * NT;            // BS*NT
    float* ocol = orow + (size_t)BS * NT;                // BS*NT

    char*  ws    = (char*)d_ws;
    float* cls   = (float*)ws;                                  // 256 KB
    float* u0    = (float*)(ws + 262144);                       // 16 KB
    float* bndp  = (float*)(ws + 278528);                       // 16 KB
    int*   jmn   = (int*)(ws + 294912);                         // 16 KB
    float* ccost = (float*)(ws + 311296);                       // 2 MB
    unsigned short* cidx = (unsigned short*)(ws + 311296 + 2097152); // 1 MB

    const size_t smem_cand  = 98304;    // 96 KB: pred(64K) + cls(32K)
    const size_t smem_fused = 132480;

    cand_kernel<<<BS * NT / 8, 512, smem_cand, stream>>>(
        logits, pred, tgt, cls, u0, jmn, bndp, ccost, cidx);
    fused_kernel<<<BS + CFB, NTHR, smem_fused, stream>>>(
        pred, tgt, cls, u0, jmn, bndp, ccost, cidx, C, orow, ocol);
}